// Round 15
// baseline (648.414 us; speedup 1.0000x reference)
//
#include <hip/hip_runtime.h>
#include <math.h>

// Problem constants
static constexpr int Bb = 128;    // batch
static constexpr int Tt = 64;     // seq len
static constexpr int Ee = 512;    // embed dim
static constexpr int Hh = 1024;   // hidden
static constexpr int Vv = 10000;  // vocab
static constexpr int G  = 4 * Hh; // 4096 gates
static constexpr int Vpad = 10240; // 40*256, zero-padded vocab rows (256-tiles)

typedef __attribute__((ext_vector_type(8))) short short8;
typedef __attribute__((ext_vector_type(4))) float floatx4;

__device__ __forceinline__ unsigned short f2bf(float f) {
    unsigned u = __float_as_uint(f);
    return (unsigned short)((u + 0x7fffu + ((u >> 16) & 1u)) >> 16);  // RNE
}
__device__ __forceinline__ float bf2f(unsigned short u) {
    return __uint_as_float((unsigned)u << 16);
}

__device__ __forceinline__ void gload16(const void* g, void* l) {
    __builtin_amdgcn_global_load_lds(
        (const __attribute__((address_space(1))) void*)g,
        (__attribute__((address_space(3))) void*)l, 16, 0, 0);
}

// fast transcendentals (v_exp_f32 + v_rcp_f32; ~1e-6 rel err, far below bf16)
__device__ __forceinline__ float sigmoid_fast(float x) {
    return __builtin_amdgcn_rcpf(1.f + __expf(-x));
}
__device__ __forceinline__ float tanh_fast(float x) {
    float e = __expf(-2.f * fabsf(x));
    float t = (1.f - e) * __builtin_amdgcn_rcpf(1.f + e);
    return copysignf(t, x);
}

// ---------------------------------------------------------------------------
// Fused prep: 3x f32->bf16 weight converts + caption/feature gather in ONE
// dispatch. Block ranges: [0,1024) W_ih | [1024,3072) W_hh |
// [3072,8192) fc_W (pad to Vpad) | [8192,10240) gather xs.
// ---------------------------------------------------------------------------
__device__ __forceinline__ void cvt8_body(const float* __restrict__ s,
                                          unsigned short* __restrict__ d,
                                          int n, int i8) {
    short8 v;
    #pragma unroll
    for (int j = 0; j < 8; ++j) {
        int e = i8 + j;
        float f = (e < n) ? s[e] : 0.f;
        v[j] = (short)f2bf(f);
    }
    *reinterpret_cast<short8*>(d + i8) = v;
}

__global__ __launch_bounds__(256)
void prep(const float* __restrict__ W_ih, const float* __restrict__ W_hh,
          const float* __restrict__ fc_W, const float* __restrict__ features,
          const int* __restrict__ captions, const float* __restrict__ embed_W,
          unsigned short* __restrict__ wihb, unsigned short* __restrict__ whhb,
          unsigned short* __restrict__ fcwb, unsigned short* __restrict__ xsb) {
    const int blk = blockIdx.x;
    const int tid = threadIdx.x;
    if (blk < 1024) {
        cvt8_body(W_ih, wihb, G * Ee, (blk * 256 + tid) * 8);
    } else if (blk < 3072) {
        cvt8_body(W_hh, whhb, G * Hh, ((blk - 1024) * 256 + tid) * 8);
    } else if (blk < 8192) {
        cvt8_body(fc_W, fcwb, Vv * Hh, ((blk - 3072) * 256 + tid) * 8);
    } else {
        int idx = (blk - 8192) * 256 + tid;     // T*B*(E/8)
        int m  = idx >> 6;                      // row, 64 chunks per row
        int c8 = (idx & 63) * 8;
        int t = m >> 7;                         // m / B
        int b = m & 127;                        // m % B
        const float* src;
        if (t == 0) {
            src = features + (size_t)b * Ee + c8;
        } else {
            int tok = captions[(size_t)b * Tt + t];
            src = embed_W + (size_t)tok * Ee + c8;
        }
        short8 v;
        #pragma unroll
        for (int j = 0; j < 8; ++j) v[j] = (short)f2bf(src[j]);
        *reinterpret_cast<short8*>(xsb + (size_t)m * Ee + c8) = v;
    }
}

// ---------------------------------------------------------------------------
// 256x256-tile bf16 MFMA GEMM, BK=32, 4-deep circular LDS pipeline,
// merged single-phase per K-tile + improved swizzle (proven 637us config).
//   MODE 1: bf16 out, C = bf16(A*B^T + bias0[n] + bias1[n])   (xg output)
//   MODE 2: f32 out[b,t,v] = A*B^T + bias0[v], m = t*B+b, guard n < N;
//           guard hoisted to wave-uniform branch (39/40 tiles unguarded).
// ---------------------------------------------------------------------------
__device__ __forceinline__ void stage_half(
    const unsigned short* __restrict__ Gsrc, int Kdim, int rowbase, int k0,
    unsigned short* ldsbase, int tid) {
    // one 16B load per thread covers the 8 KB half-tile (128 rows x 32 k)
    int e = tid * 16;                     // byte offset in half-tile
    int r = e >> 6;                       // row 0..127
    int c = e & 63;                       // byte in row (0/16/32/48)
    int c_log = c ^ (((r >> 1) & 3) << 4); // inverse-swizzled source column
    gload16(Gsrc + (size_t)(rowbase + r) * Kdim + k0 + (c_log >> 1),
            ldsbase + tid * 8);
}

template<int MODE>
__global__ __launch_bounds__(512, 2)
void gemm256(const unsigned short* __restrict__ A,
             const unsigned short* __restrict__ Bm,
             int M, int N, int K,
             const float* __restrict__ bias0, const float* __restrict__ bias1,
             void* __restrict__ Cv) {
    constexpr int BK = 32;
    __shared__ unsigned short lds[4 * 2 * 256 * BK];   // 128 KB

    const int nwg = gridDim.x * gridDim.y;
    const int flat = blockIdx.y * gridDim.x + blockIdx.x;
    const int tix = (flat & 7) * (nwg >> 3) + (flat >> 3);
    const int bx = tix % gridDim.x;
    const int by = tix / gridDim.x;

    const int tid  = threadIdx.x;
    const int wid  = tid >> 6;      // 0..7
    const int lane = tid & 63;
    const int wm = wid >> 2;        // 0..1  (M half)
    const int wn = wid & 3;         // 0..3  (N quarter)
    const int row0 = bx * 256;
    const int col0 = by * 256;
    const int l15 = lane & 15;
    const int kq  = lane >> 4;

    const int NT = K / BK;

    // per-thread ds_read bases (shorts); swizzled slot kq ^ ((l15>>1)&3)
    const int swz = (kq ^ ((l15 >> 1) & 3)) * 8;
    const int arow_s = wm * 4096 + l15 * 32 + swz;
    const int brow_s = 8192 + (wn >> 1) * 4096 + ((wn & 1) * 64 + l15) * 32 + swz;

    floatx4 acc[8][4];
    #pragma unroll
    for (int i = 0; i < 8; ++i)
        #pragma unroll
        for (int j = 0; j < 4; ++j) acc[i][j] = (floatx4)0.f;

    // prologue: stage tiles 0 and 1 (4 half-tiles each)
    stage_half(A,  K, row0,       0,  &lds[0],     tid);
    stage_half(A,  K, row0 + 128, 0,  &lds[4096],  tid);
    stage_half(Bm, K, col0,       0,  &lds[8192],  tid);
    stage_half(Bm, K, col0 + 128, 0,  &lds[12288], tid);
    stage_half(A,  K, row0,       BK, &lds[16384 + 0],     tid);
    stage_half(A,  K, row0 + 128, BK, &lds[16384 + 4096],  tid);
    stage_half(Bm, K, col0,       BK, &lds[16384 + 8192],  tid);
    stage_half(Bm, K, col0 + 128, BK, &lds[16384 + 12288], tid);
    asm volatile("s_waitcnt vmcnt(4)" ::: "memory");   // tile 0 landed
    asm volatile("s_barrier" ::: "memory");

    for (int t = 0; t < NT; ++t) {
        const int cur = (t & 3) * 16384;
        short8 af[8], bfr[4];
        #pragma unroll
        for (int fi = 0; fi < 8; ++fi)
            af[fi] = *reinterpret_cast<const short8*>(&lds[cur + arow_s + fi * 512]);
        #pragma unroll
        for (int fj = 0; fj < 4; ++fj)
            bfr[fj] = *reinterpret_cast<const short8*>(&lds[cur + brow_s + fj * 512]);
        if (t + 2 < NT) {   // stage tile t+2 into buf[(t+2)&3]
            const int nb = ((t + 2) & 3) * 16384;
            stage_half(A,  K, row0,       (t + 2) * BK, &lds[nb],         tid);
            stage_half(A,  K, row0 + 128, (t + 2) * BK, &lds[nb + 4096],  tid);
            stage_half(Bm, K, col0,       (t + 2) * BK, &lds[nb + 8192],  tid);
            stage_half(Bm, K, col0 + 128, (t + 2) * BK, &lds[nb + 12288], tid);
        }
        __builtin_amdgcn_s_setprio(1);
        #pragma unroll
        for (int fi = 0; fi < 8; ++fi)
            #pragma unroll
            for (int fj = 0; fj < 4; ++fj)
                acc[fi][fj] = __builtin_amdgcn_mfma_f32_16x16x32_bf16(
                    af[fi], bfr[fj], acc[fi][fj], 0, 0, 0);
        __builtin_amdgcn_s_setprio(0);
        if (t + 1 < NT) {
            if (t + 2 < NT) asm volatile("s_waitcnt vmcnt(4)" ::: "memory");
            else            asm volatile("s_waitcnt vmcnt(0)" ::: "memory");
            asm volatile("s_barrier" ::: "memory");
        }
    }

    // epilogue
    if (MODE == 1) {
        unsigned short* C = (unsigned short*)Cv;
        #pragma unroll
        for (int fi = 0; fi < 8; ++fi)
            #pragma unroll
            for (int fj = 0; fj < 4; ++fj)
                #pragma unroll
                for (int q = 0; q < 4; ++q) {
                    int m = row0 + wm * 128 + fi * 16 + kq * 4 + q;
                    int n = col0 + wn * 64 + fj * 16 + l15;
                    C[(size_t)m * N + n] =
                        f2bf(acc[fi][fj][q] + bias0[n] + bias1[n]);
                }
    } else {
        float* C = (float*)Cv;
        if (col0 + 256 <= N) {
            // fast path: whole tile in-bounds (wave-uniform), no per-elem guard
            #pragma unroll
            for (int fi = 0; fi < 8; ++fi)
                #pragma unroll
                for (int fj = 0; fj < 4; ++fj)
                    #pragma unroll
                    for (int q = 0; q < 4; ++q) {
                        int m = row0 + wm * 128 + fi * 16 + kq * 4 + q;
                        int n = col0 + wn * 64 + fj * 16 + l15;
                        int t = m >> 7, b = m & 127;
                        C[(size_t)b * (Tt * Vv) + (size_t)t * Vv + n] =
                            acc[fi][fj][q] + bias0[n];
                    }
        } else {
            #pragma unroll
            for (int fi = 0; fi < 8; ++fi)
                #pragma unroll
                for (int fj = 0; fj < 4; ++fj)
                    #pragma unroll
                    for (int q = 0; q < 4; ++q) {
                        int m = row0 + wm * 128 + fi * 16 + kq * 4 + q;
                        int n = col0 + wn * 64 + fj * 16 + l15;
                        if (n < N) {
                            int t = m >> 7, b = m & 127;
                            C[(size_t)b * (Tt * Vv) + (size_t)t * Vv + n] =
                                acc[fi][fj][q] + bias0[n];
                        }
                    }
        }
    }
}

// ---------------------------------------------------------------------------
// v13 gate MFMA (proven): W operands in REGISTERS (wreg[8][4] short8 =
// 128 VGPR), rotated h-gather. All indices compile-time.
// ---------------------------------------------------------------------------
template<int ROT>
__device__ __forceinline__ void gate_mfma(
    const unsigned short* __restrict__ hprev,
    const short8 (&wreg)[8][4],
    int row0, int wave, int l15, int kq,
    floatx4 (&acc)[2][4])
{
    const short8* ar0 = reinterpret_cast<const short8*>(
        hprev + (size_t)(row0 + l15) * Hh) + wave * 32 + kq;
    const short8* ar1 = reinterpret_cast<const short8*>(
        hprev + (size_t)(row0 + 16 + l15) * Hh) + wave * 32 + kq;
    short8 a0[8], a1[8];
    #pragma unroll
    for (int ks = 0; ks < 8; ++ks) {
        const int j = (ks + ROT) & 7;
        a0[ks] = ar0[j * 4];
        a1[ks] = ar1[j * 4];
    }
    #pragma unroll
    for (int ks = 0; ks < 8; ++ks) {
        const int j = (ks + ROT) & 7;
        acc[0][0] = __builtin_amdgcn_mfma_f32_16x16x32_bf16(
            a0[ks], wreg[j][0], acc[0][0], 0, 0, 0);
        acc[0][1] = __builtin_amdgcn_mfma_f32_16x16x32_bf16(
            a0[ks], wreg[j][1], acc[0][1], 0, 0, 0);
        acc[0][2] = __builtin_amdgcn_mfma_f32_16x16x32_bf16(
            a0[ks], wreg[j][2], acc[0][2], 0, 0, 0);
        acc[0][3] = __builtin_amdgcn_mfma_f32_16x16x32_bf16(
            a0[ks], wreg[j][3], acc[0][3], 0, 0, 0);
    }
    #pragma unroll
    for (int ks = 0; ks < 8; ++ks) {
        const int j = (ks + ROT) & 7;
        acc[1][0] = __builtin_amdgcn_mfma_f32_16x16x32_bf16(
            a1[ks], wreg[j][0], acc[1][0], 0, 0, 0);
        acc[1][1] = __builtin_amdgcn_mfma_f32_16x16x32_bf16(
            a1[ks], wreg[j][1], acc[1][1], 0, 0, 0);
        acc[1][2] = __builtin_amdgcn_mfma_f32_16x16x32_bf16(
            a1[ks], wreg[j][2], acc[1][2], 0, 0, 0);
        acc[1][3] = __builtin_amdgcn_mfma_f32_16x16x32_bf16(
            a1[ks], wreg[j][3], acc[1][3], 0, 0, 0);
    }
}

// ---------------------------------------------------------------------------
// Persistent LSTM recurrence, v13 FROZEN (proven 338-341 us) with ONE
// traffic-only edit: xg is now bf16 (loads convert via bf2f). Ownership,
// reduction, sync, and MFMA algebra untouched.
// DO NOT restructure ownership/reduction: v9, v14, v15 all failed
// correctness (absmax 0.12-0.38) on rewrites of this logic; v12's sync
// change regressed 50%. Wins came only from traffic changes (v8 WG-count,
// v11 rotation, v13 W-in-regs) that kept the v8 ownership algebra intact.
// ---------------------------------------------------------------------------
__global__ __launch_bounds__(256, 1)
void lstm_persist(const unsigned short* __restrict__ whhb, // [4096][1024] bf16
                  const unsigned short* __restrict__ xg,   // [64*128][4096] bf16
                  unsigned short* __restrict__ hsb,        // [64][128][1024] bf16
                  unsigned* __restrict__ flags) {          // 32 ctrs, 64B stride
    __shared__ float redsum[8 * 3 * 4 * 64];        // 24 KB  [c][slot][nb][lane]
    const int tid  = threadIdx.x;
    const int w    = blockIdx.x;
    const int wg_m = w & 3;        // row cohort: rows [wg_m*32, +32)
    const int wg_n = w >> 2;       // hcol slice (0..63)
    const int wave = tid >> 6;
    const int lane = tid & 63;
    const int l15  = lane & 15;
    const int kq   = lane >> 4;

    const int row0 = wg_m * 32;
    const int hcol = wg_n * 16 + l15;
    const int lrA = (wave >> 1) * 16 + kq * 4 + ((wave & 1) * 2);
    const int lrB = lrA + 1;
    const int rotsel = (wg_n >> 1) & 3;   // cycles 0..3 within an XCD
    unsigned* myctr = flags + (size_t)(wg_m * 8 + (wg_n >> 3)) * 16;
    float cell0 = 0.f, cell1 = 0.f;

    // W_hh fragments in registers, loaded once:
    // wreg[j][nb] = whhb[(nb*1024 + wg_n*16 + l15)*1024 + (wave*32+j*4+kq)*8]
    short8 wreg[8][4];
    {
        const unsigned short* wbase = whhb
            + (size_t)(wg_n * 16 + l15) * Hh + wave * 256 + kq * 8;
        #pragma unroll
        for (int nb = 0; nb < 4; ++nb)
            #pragma unroll
            for (int j = 0; j < 8; ++j)
                wreg[j][nb] = *reinterpret_cast<const short8*>(
                    wbase + (size_t)nb * Hh * Hh + j * 32);
    }

    float xa[2][4], xb[2][4];
    {
        const unsigned short* xr = xg + (size_t)(row0 + lrA) * G
                                 + wg_n * 16 + l15;
        #pragma unroll
        for (int nb = 0; nb < 4; ++nb) {
            xa[0][nb] = bf2f(xr[nb * Hh]);
            xa[1][nb] = bf2f(xr[G + nb * Hh]);
        }
    }

#define WRC(W_, C_)                                                            \
    if (((C_) >> 1) != (W_)) {                                                 \
        _Pragma("unroll")                                                      \
        for (int nb = 0; nb < 4; ++nb)                                         \
            redsum[((C_) * 3 + (((W_) > ((C_) >> 1)) ? (W_)-1 : (W_))) * 256   \
                   + nb * 64 + lane] = acc[(C_) >> 2][nb][(C_) & 3];           \
    }

#define SPILL(W_)                                                              \
    do {                                                                       \
        _Pragma("unroll")                                                      \
        for (int nb = 0; nb < 4; ++nb) {                                       \
            own0[nb] = acc[(2 * (W_)) >> 2][nb][(2 * (W_)) & 3];               \
            own1[nb] = acc[(2 * (W_) + 1) >> 2][nb][(2 * (W_) + 1) & 3];       \
        }                                                                      \
        WRC(W_, 0); WRC(W_, 1); WRC(W_, 2); WRC(W_, 3);                        \
        WRC(W_, 4); WRC(W_, 5); WRC(W_, 6); WRC(W_, 7);                        \
    } while (0)

#define LSTM_STEP(T, XC, XN)                                                   \
    do {                                                                       \
        const int t_ = (T);                                                    \
        floatx4 acc[2][4];                                                     \
        _Pragma("unroll")                                                      \
        for (int i = 0; i < 2; ++i)                                            \
            _Pragma("unroll")                                                  \
            for (int j = 0; j < 4; ++j) acc[i][j] = (floatx4)0.f;              \
        if (t_ > 0) {                                                          \
            if (tid < 8) {                                                     \
                const unsigned* fl = flags + (size_t)(wg_m * 8 + tid) * 16;    \
                unsigned need = 8u * (unsigned)t_;                             \
                while (__hip_atomic_load(fl, __ATOMIC_RELAXED,                 \
                                         __HIP_MEMORY_SCOPE_AGENT) < need)     \
                    __builtin_amdgcn_s_sleep(1);                               \
            }                                                                  \
            __syncthreads();                                                   \
            asm volatile("" ::: "memory");                                     \
            const unsigned short* hprev = hsb + (size_t)(t_ - 1) * (Bb * Hh);  \
            if (rotsel == 0)                                                   \
                gate_mfma<0>(hprev, wreg, row0, wave, l15, kq, acc);           \
            else if (rotsel == 1)                                              \
                gate_mfma<2>(hprev, wreg, row0, wave, l15, kq, acc);           \
            else if (rotsel == 2)                                              \
                gate_mfma<4>(hprev, wreg, row0, wave, l15, kq, acc);           \
            else                                                               \
                gate_mfma<6>(hprev, wreg, row0, wave, l15, kq, acc);           \
        }                                                                      \
        float own0[4], own1[4];                                                \
        if (wave == 0)      SPILL(0);                                          \
        else if (wave == 1) SPILL(1);                                          \
        else if (wave == 2) SPILL(2);                                          \
        else                SPILL(3);                                          \
        __syncthreads();                                                       \
        float gA[4], gB[4];                                                    \
        {                                                                      \
            const int cA = wave * 2;                                           \
            _Pragma("unroll")                                                  \
            for (int nb = 0; nb < 4; ++nb) {                                   \
                int bA = (cA * 3) * 256 + nb * 64 + lane;                      \
                gA[nb] = own0[nb] + redsum[bA] + redsum[bA + 256]              \
                       + redsum[bA + 512] + XC[0][nb];                         \
                int bB = ((cA + 1) * 3) * 256 + nb * 64 + lane;                \
                gB[nb] = own1[nb] + redsum[bB] + redsum[bB + 256]              \
                       + redsum[bB + 512] + XC[1][nb];                         \
            }                                                                  \
        }                                                                      \
        unsigned short* ht = hsb + (size_t)t_ * (Bb * Hh);                     \
        {                                                                      \
            float si = sigmoid_fast(gA[0]);                                    \
            float sf = sigmoid_fast(gA[1]);                                    \
            float tg = tanh_fast(gA[2]);                                       \
            float so = sigmoid_fast(gA[3]);                                    \
            float cn = sf * cell0 + si * tg;                                   \
            cell0 = cn;                                                        \
            float h = so * tanh_fast(cn);                                      \
            __hip_atomic_store(&ht[(size_t)(row0 + lrA) * Hh + hcol], f2bf(h), \
                               __ATOMIC_RELAXED, __HIP_MEMORY_SCOPE_AGENT);    \
        }                                                                      \
        {                                                                      \
            float si = sigmoid_fast(gB[0]);                                    \
            float sf = sigmoid_fast(gB[1]);                                    \
            float tg = tanh_fast(gB[2]);                                       \
            float so = sigmoid_fast(gB[3]);                                    \
            float cn = sf * cell1 + si * tg;                                   \
            cell1 = cn;                                                        \
            float h = so * tanh_fast(cn);                                      \
            __hip_atomic_store(&ht[(size_t)(row0 + lrB) * Hh + hcol], f2bf(h), \
                               __ATOMIC_RELAXED, __HIP_MEMORY_SCOPE_AGENT);    \
        }                                                                      \
        __builtin_amdgcn_sched_barrier(0);                                     \
        if (t_ + 1 < Tt) {   /* xg prefetch: YOUNGEST VMEM (after stores) */   \
            const unsigned short* xr = xg + (size_t)(t_ + 1) * (Bb * G)        \
                + (size_t)(row0 + lrA) * G + wg_n * 16 + l15;                  \
            _Pragma("unroll")                                                  \
            for (int nb = 0; nb < 4; ++nb) {                                   \
                XN[0][nb] = bf2f(xr[nb * Hh]);                                 \
                XN[1][nb] = bf2f(xr[G + nb * Hh]);                             \
            }                                                                  \
        }                                                                      \
        __builtin_amdgcn_sched_barrier(0);                                     \
        if (t_ < Tt - 1) {                                                     \
            /* 2 h stores (oldest) + 8 xg loads outstanding: wait stores */    \
            asm volatile("s_waitcnt vmcnt(8)" ::: "memory");                   \
            __builtin_amdgcn_sched_barrier(0);                                 \
            __builtin_amdgcn_s_barrier();                                      \
            __builtin_amdgcn_sched_barrier(0);                                 \
            if (tid == 0)                                                      \
                __hip_atomic_fetch_add(myctr, 1u, __ATOMIC_RELAXED,            \
                                       __HIP_MEMORY_SCOPE_AGENT);              \
        }                                                                      \
    } while (0)

    for (int tt = 0; tt < Tt; tt += 2) {
        LSTM_STEP(tt,     xa, xb);
        LSTM_STEP(tt + 1, xb, xa);
    }
#undef LSTM_STEP
#undef SPILL
#undef WRC
}

// ---------------------------------------------------------------------------
extern "C" void kernel_launch(void* const* d_in, const int* in_sizes, int n_in,
                              void* d_out, int out_size, void* d_ws, size_t ws_size,
                              hipStream_t stream) {
    const float* features = (const float*)d_in[0];
    const int*   captions = (const int*)d_in[1];
    const float* embed_W  = (const float*)d_in[2];
    const float* W_ih     = (const float*)d_in[3];
    const float* W_hh     = (const float*)d_in[4];
    const float* b_ih     = (const float*)d_in[5];
    const float* b_hh     = (const float*)d_in[6];
    const float* fc_W     = (const float*)d_in[7];
    const float* fc_b     = (const float*)d_in[8];
    float* out = (float*)d_out;

    unsigned short* xsb  = (unsigned short*)d_ws;          // [8192][512]
    unsigned short* wihb = xsb  + (size_t)Tt * Bb * Ee;    // [4096][512]
    unsigned short* whhb = wihb + (size_t)G * Ee;          // [4096][1024]
    unsigned short* fcwb = whhb + (size_t)G * Hh;          // [10240][1024]
    unsigned short* hsb  = fcwb + (size_t)Vpad * Hh;       // [64][128][1024]
    unsigned short* xgb  = hsb + (size_t)Tt * Bb * Hh;     // [8192][4096] bf16
    unsigned* flags = (unsigned*)(xgb + (size_t)Tt * Bb * G); // 32 ctrs

    (void)hipMemsetAsync(flags, 0, 128 * 32 * sizeof(unsigned), stream);

    // 1) fused weight conversions + input gather (one dispatch)
    prep<<<10240, 256, 0, stream>>>(W_ih, W_hh, fc_W, features, captions,
                                    embed_W, wihb, whhb, fcwb, xsb);

    // 2) x_gates = bf16(xs @ W_ih^T + b_ih + b_hh)   (M=8192, N=4096, K=512)
    {
        dim3 grid(8192 / 256, G / 256);   // 32 x 16 = 512 wgs (%8 == 0)
        gemm256<1><<<grid, 512, 0, stream>>>(
            xsb, wihb, 8192, G, Ee, b_ih, b_hh, (void*)xgb);
    }

    // 3) persistent LSTM recurrence (one launch, 64 steps, all 256 CUs)
    lstm_persist<<<256, 256, 0, stream>>>(whhb, xgb, hsb, flags);

    // 4) out[b,t,v] = hs @ fc_W^T + fc_b   (M=8192, N=10000(pad 10240), K=1024)
    {
        dim3 grid(8192 / 256, Vpad / 256);  // 32 x 40 = 1280 wgs (%8 == 0)
        gemm256<2><<<grid, 512, 0, stream>>>(
            hsb, fcwb, 8192, Vv, Hh, fc_b, nullptr, (void*)out);
    }
}

// Round 16
// 620.246 us; speedup vs baseline: 1.0454x; 1.0454x over previous
//
#include <hip/hip_runtime.h>
#include <math.h>

// Problem constants
static constexpr int Bb = 128;    // batch
static constexpr int Tt = 64;     // seq len
static constexpr int Ee = 512;    // embed dim
static constexpr int Hh = 1024;   // hidden
static constexpr int Vv = 10000;  // vocab
static constexpr int G  = 4 * Hh; // 4096 gates
static constexpr int Vpad = 10240; // 40*256, zero-padded vocab rows (256-tiles)

typedef __attribute__((ext_vector_type(8))) short short8;
typedef __attribute__((ext_vector_type(4))) float floatx4;

__device__ __forceinline__ unsigned short f2bf(float f) {
    unsigned u = __float_as_uint(f);
    return (unsigned short)((u + 0x7fffu + ((u >> 16) & 1u)) >> 16);  // RNE
}
__device__ __forceinline__ float bf2f(unsigned short u) {
    return __uint_as_float((unsigned)u << 16);
}

__device__ __forceinline__ void gload16(const void* g, void* l) {
    __builtin_amdgcn_global_load_lds(
        (const __attribute__((address_space(1))) void*)g,
        (__attribute__((address_space(3))) void*)l, 16, 0, 0);
}

// non-temporal f32 store: output is never re-read on-device; nt keeps the
// 327MB out-stream from evicting the A/B GEMM panels out of the XCD L2.
__device__ __forceinline__ void store_nt(float* p, float v) {
    asm volatile("global_store_dword %0, %1, off nt"
                 :: "v"((unsigned long long)(uintptr_t)p), "v"(v) : "memory");
}

// fast transcendentals (v_exp_f32 + v_rcp_f32; ~1e-6 rel err, far below bf16)
__device__ __forceinline__ float sigmoid_fast(float x) {
    return __builtin_amdgcn_rcpf(1.f + __expf(-x));
}
__device__ __forceinline__ float tanh_fast(float x) {
    float e = __expf(-2.f * fabsf(x));
    float t = (1.f - e) * __builtin_amdgcn_rcpf(1.f + e);
    return copysignf(t, x);
}

// ---------------------------------------------------------------------------
// Fused prep: 3x f32->bf16 weight converts + caption/feature gather in ONE
// dispatch. Block ranges: [0,1024) W_ih | [1024,3072) W_hh |
// [3072,8192) fc_W (pad to Vpad) | [8192,10240) gather xs.
// ---------------------------------------------------------------------------
__device__ __forceinline__ void cvt8_body(const float* __restrict__ s,
                                          unsigned short* __restrict__ d,
                                          int n, int i8) {
    short8 v;
    #pragma unroll
    for (int j = 0; j < 8; ++j) {
        int e = i8 + j;
        float f = (e < n) ? s[e] : 0.f;
        v[j] = (short)f2bf(f);
    }
    *reinterpret_cast<short8*>(d + i8) = v;
}

__global__ __launch_bounds__(256)
void prep(const float* __restrict__ W_ih, const float* __restrict__ W_hh,
          const float* __restrict__ fc_W, const float* __restrict__ features,
          const int* __restrict__ captions, const float* __restrict__ embed_W,
          unsigned short* __restrict__ wihb, unsigned short* __restrict__ whhb,
          unsigned short* __restrict__ fcwb, unsigned short* __restrict__ xsb) {
    const int blk = blockIdx.x;
    const int tid = threadIdx.x;
    if (blk < 1024) {
        cvt8_body(W_ih, wihb, G * Ee, (blk * 256 + tid) * 8);
    } else if (blk < 3072) {
        cvt8_body(W_hh, whhb, G * Hh, ((blk - 1024) * 256 + tid) * 8);
    } else if (blk < 8192) {
        cvt8_body(fc_W, fcwb, Vv * Hh, ((blk - 3072) * 256 + tid) * 8);
    } else {
        int idx = (blk - 8192) * 256 + tid;     // T*B*(E/8)
        int m  = idx >> 6;                      // row, 64 chunks per row
        int c8 = (idx & 63) * 8;
        int t = m >> 7;                         // m / B
        int b = m & 127;                        // m % B
        const float* src;
        if (t == 0) {
            src = features + (size_t)b * Ee + c8;
        } else {
            int tok = captions[(size_t)b * Tt + t];
            src = embed_W + (size_t)tok * Ee + c8;
        }
        short8 v;
        #pragma unroll
        for (int j = 0; j < 8; ++j) v[j] = (short)f2bf(src[j]);
        *reinterpret_cast<short8*>(xsb + (size_t)m * Ee + c8) = v;
    }
}

// ---------------------------------------------------------------------------
// 256x256-tile bf16 MFMA GEMM, BK=32, 4-deep circular LDS pipeline,
// merged single-phase per K-tile + improved swizzle (proven config).
//   MODE 1: bf16 out, C = bf16(A*B^T + bias0[n] + bias1[n])   (xg output)
//   MODE 2: f32 out[b,t,v] = A*B^T + bias0[v], m = t*B+b, guard n < N;
//           guard hoisted wave-uniform; stores are NON-TEMPORAL (nt).
// ---------------------------------------------------------------------------
__device__ __forceinline__ void stage_half(
    const unsigned short* __restrict__ Gsrc, int Kdim, int rowbase, int k0,
    unsigned short* ldsbase, int tid) {
    // one 16B load per thread covers the 8 KB half-tile (128 rows x 32 k)
    int e = tid * 16;                     // byte offset in half-tile
    int r = e >> 6;                       // row 0..127
    int c = e & 63;                       // byte in row (0/16/32/48)
    int c_log = c ^ (((r >> 1) & 3) << 4); // inverse-swizzled source column
    gload16(Gsrc + (size_t)(rowbase + r) * Kdim + k0 + (c_log >> 1),
            ldsbase + tid * 8);
}

template<int MODE>
__global__ __launch_bounds__(512, 2)
void gemm256(const unsigned short* __restrict__ A,
             const unsigned short* __restrict__ Bm,
             int M, int N, int K,
             const float* __restrict__ bias0, const float* __restrict__ bias1,
             void* __restrict__ Cv) {
    constexpr int BK = 32;
    __shared__ unsigned short lds[4 * 2 * 256 * BK];   // 128 KB

    const int nwg = gridDim.x * gridDim.y;
    const int flat = blockIdx.y * gridDim.x + blockIdx.x;
    const int tix = (flat & 7) * (nwg >> 3) + (flat >> 3);
    const int bx = tix % gridDim.x;
    const int by = tix / gridDim.x;

    const int tid  = threadIdx.x;
    const int wid  = tid >> 6;      // 0..7
    const int lane = tid & 63;
    const int wm = wid >> 2;        // 0..1  (M half)
    const int wn = wid & 3;         // 0..3  (N quarter)
    const int row0 = bx * 256;
    const int col0 = by * 256;
    const int l15 = lane & 15;
    const int kq  = lane >> 4;

    const int NT = K / BK;

    // per-thread ds_read bases (shorts); swizzled slot kq ^ ((l15>>1)&3)
    const int swz = (kq ^ ((l15 >> 1) & 3)) * 8;
    const int arow_s = wm * 4096 + l15 * 32 + swz;
    const int brow_s = 8192 + (wn >> 1) * 4096 + ((wn & 1) * 64 + l15) * 32 + swz;

    floatx4 acc[8][4];
    #pragma unroll
    for (int i = 0; i < 8; ++i)
        #pragma unroll
        for (int j = 0; j < 4; ++j) acc[i][j] = (floatx4)0.f;

    // prologue: stage tiles 0 and 1 (4 half-tiles each)
    stage_half(A,  K, row0,       0,  &lds[0],     tid);
    stage_half(A,  K, row0 + 128, 0,  &lds[4096],  tid);
    stage_half(Bm, K, col0,       0,  &lds[8192],  tid);
    stage_half(Bm, K, col0 + 128, 0,  &lds[12288], tid);
    stage_half(A,  K, row0,       BK, &lds[16384 + 0],     tid);
    stage_half(A,  K, row0 + 128, BK, &lds[16384 + 4096],  tid);
    stage_half(Bm, K, col0,       BK, &lds[16384 + 8192],  tid);
    stage_half(Bm, K, col0 + 128, BK, &lds[16384 + 12288], tid);
    asm volatile("s_waitcnt vmcnt(4)" ::: "memory");   // tile 0 landed
    asm volatile("s_barrier" ::: "memory");

    for (int t = 0; t < NT; ++t) {
        const int cur = (t & 3) * 16384;
        short8 af[8], bfr[4];
        #pragma unroll
        for (int fi = 0; fi < 8; ++fi)
            af[fi] = *reinterpret_cast<const short8*>(&lds[cur + arow_s + fi * 512]);
        #pragma unroll
        for (int fj = 0; fj < 4; ++fj)
            bfr[fj] = *reinterpret_cast<const short8*>(&lds[cur + brow_s + fj * 512]);
        if (t + 2 < NT) {   // stage tile t+2 into buf[(t+2)&3]
            const int nb = ((t + 2) & 3) * 16384;
            stage_half(A,  K, row0,       (t + 2) * BK, &lds[nb],         tid);
            stage_half(A,  K, row0 + 128, (t + 2) * BK, &lds[nb + 4096],  tid);
            stage_half(Bm, K, col0,       (t + 2) * BK, &lds[nb + 8192],  tid);
            stage_half(Bm, K, col0 + 128, (t + 2) * BK, &lds[nb + 12288], tid);
        }
        __builtin_amdgcn_s_setprio(1);
        #pragma unroll
        for (int fi = 0; fi < 8; ++fi)
            #pragma unroll
            for (int fj = 0; fj < 4; ++fj)
                acc[fi][fj] = __builtin_amdgcn_mfma_f32_16x16x32_bf16(
                    af[fi], bfr[fj], acc[fi][fj], 0, 0, 0);
        __builtin_amdgcn_s_setprio(0);
        if (t + 1 < NT) {
            if (t + 2 < NT) asm volatile("s_waitcnt vmcnt(4)" ::: "memory");
            else            asm volatile("s_waitcnt vmcnt(0)" ::: "memory");
            asm volatile("s_barrier" ::: "memory");
        }
    }

    // epilogue
    if (MODE == 1) {
        unsigned short* C = (unsigned short*)Cv;
        #pragma unroll
        for (int fi = 0; fi < 8; ++fi)
            #pragma unroll
            for (int fj = 0; fj < 4; ++fj)
                #pragma unroll
                for (int q = 0; q < 4; ++q) {
                    int m = row0 + wm * 128 + fi * 16 + kq * 4 + q;
                    int n = col0 + wn * 64 + fj * 16 + l15;
                    C[(size_t)m * N + n] =
                        f2bf(acc[fi][fj][q] + bias0[n] + bias1[n]);
                }
    } else {
        float* C = (float*)Cv;
        if (col0 + 256 <= N) {
            // fast path: whole tile in-bounds (wave-uniform); nt stores
            #pragma unroll
            for (int fi = 0; fi < 8; ++fi)
                #pragma unroll
                for (int fj = 0; fj < 4; ++fj)
                    #pragma unroll
                    for (int q = 0; q < 4; ++q) {
                        int m = row0 + wm * 128 + fi * 16 + kq * 4 + q;
                        int n = col0 + wn * 64 + fj * 16 + l15;
                        int t = m >> 7, b = m & 127;
                        store_nt(&C[(size_t)b * (Tt * Vv) + (size_t)t * Vv + n],
                                 acc[fi][fj][q] + bias0[n]);
                    }
        } else {
            #pragma unroll
            for (int fi = 0; fi < 8; ++fi)
                #pragma unroll
                for (int fj = 0; fj < 4; ++fj)
                    #pragma unroll
                    for (int q = 0; q < 4; ++q) {
                        int m = row0 + wm * 128 + fi * 16 + kq * 4 + q;
                        int n = col0 + wn * 64 + fj * 16 + l15;
                        if (n < N) {
                            int t = m >> 7, b = m & 127;
                            store_nt(&C[(size_t)b * (Tt * Vv)
                                        + (size_t)t * Vv + n],
                                     acc[fi][fj][q] + bias0[n]);
                        }
                    }
        }
    }
}

// ---------------------------------------------------------------------------
// v13 gate MFMA (proven): W operands in REGISTERS (wreg[8][4] short8 =
// 128 VGPR), rotated h-gather. All indices compile-time.
// ---------------------------------------------------------------------------
template<int ROT>
__device__ __forceinline__ void gate_mfma(
    const unsigned short* __restrict__ hprev,
    const short8 (&wreg)[8][4],
    int row0, int wave, int l15, int kq,
    floatx4 (&acc)[2][4])
{
    const short8* ar0 = reinterpret_cast<const short8*>(
        hprev + (size_t)(row0 + l15) * Hh) + wave * 32 + kq;
    const short8* ar1 = reinterpret_cast<const short8*>(
        hprev + (size_t)(row0 + 16 + l15) * Hh) + wave * 32 + kq;
    short8 a0[8], a1[8];
    #pragma unroll
    for (int ks = 0; ks < 8; ++ks) {
        const int j = (ks + ROT) & 7;
        a0[ks] = ar0[j * 4];
        a1[ks] = ar1[j * 4];
    }
    #pragma unroll
    for (int ks = 0; ks < 8; ++ks) {
        const int j = (ks + ROT) & 7;
        acc[0][0] = __builtin_amdgcn_mfma_f32_16x16x32_bf16(
            a0[ks], wreg[j][0], acc[0][0], 0, 0, 0);
        acc[0][1] = __builtin_amdgcn_mfma_f32_16x16x32_bf16(
            a0[ks], wreg[j][1], acc[0][1], 0, 0, 0);
        acc[0][2] = __builtin_amdgcn_mfma_f32_16x16x32_bf16(
            a0[ks], wreg[j][2], acc[0][2], 0, 0, 0);
        acc[0][3] = __builtin_amdgcn_mfma_f32_16x16x32_bf16(
            a0[ks], wreg[j][3], acc[0][3], 0, 0, 0);
    }
    #pragma unroll
    for (int ks = 0; ks < 8; ++ks) {
        const int j = (ks + ROT) & 7;
        acc[1][0] = __builtin_amdgcn_mfma_f32_16x16x32_bf16(
            a1[ks], wreg[j][0], acc[1][0], 0, 0, 0);
        acc[1][1] = __builtin_amdgcn_mfma_f32_16x16x32_bf16(
            a1[ks], wreg[j][1], acc[1][1], 0, 0, 0);
        acc[1][2] = __builtin_amdgcn_mfma_f32_16x16x32_bf16(
            a1[ks], wreg[j][2], acc[1][2], 0, 0, 0);
        acc[1][3] = __builtin_amdgcn_mfma_f32_16x16x32_bf16(
            a1[ks], wreg[j][3], acc[1][3], 0, 0, 0);
    }
}

// ---------------------------------------------------------------------------
// Persistent LSTM recurrence, v13 FROZEN (proven 335-341 us) with bf16 xg
// (traffic-only edit, R15 proven: FETCH 164->98.7 GB). Ownership, reduction,
// sync, and MFMA algebra untouched.
// DO NOT restructure ownership/reduction: v9, v14, v15 all failed
// correctness (absmax 0.12-0.38) on rewrites of this logic; v12's sync
// change regressed 50%. Wins came only from traffic changes (v8 WG-count,
// v11 rotation, v13 W-in-regs) that kept the v8 ownership algebra intact.
// ---------------------------------------------------------------------------
__global__ __launch_bounds__(256, 1)
void lstm_persist(const unsigned short* __restrict__ whhb, // [4096][1024] bf16
                  const unsigned short* __restrict__ xg,   // [64*128][4096] bf16
                  unsigned short* __restrict__ hsb,        // [64][128][1024] bf16
                  unsigned* __restrict__ flags) {          // 32 ctrs, 64B stride
    __shared__ float redsum[8 * 3 * 4 * 64];        // 24 KB  [c][slot][nb][lane]
    const int tid  = threadIdx.x;
    const int w    = blockIdx.x;
    const int wg_m = w & 3;        // row cohort: rows [wg_m*32, +32)
    const int wg_n = w >> 2;       // hcol slice (0..63)
    const int wave = tid >> 6;
    const int lane = tid & 63;
    const int l15  = lane & 15;
    const int kq   = lane >> 4;

    const int row0 = wg_m * 32;
    const int hcol = wg_n * 16 + l15;
    const int lrA = (wave >> 1) * 16 + kq * 4 + ((wave & 1) * 2);
    const int lrB = lrA + 1;
    const int rotsel = (wg_n >> 1) & 3;   // cycles 0..3 within an XCD
    unsigned* myctr = flags + (size_t)(wg_m * 8 + (wg_n >> 3)) * 16;
    float cell0 = 0.f, cell1 = 0.f;

    // W_hh fragments in registers, loaded once:
    // wreg[j][nb] = whhb[(nb*1024 + wg_n*16 + l15)*1024 + (wave*32+j*4+kq)*8]
    short8 wreg[8][4];
    {
        const unsigned short* wbase = whhb
            + (size_t)(wg_n * 16 + l15) * Hh + wave * 256 + kq * 8;
        #pragma unroll
        for (int nb = 0; nb < 4; ++nb)
            #pragma unroll
            for (int j = 0; j < 8; ++j)
                wreg[j][nb] = *reinterpret_cast<const short8*>(
                    wbase + (size_t)nb * Hh * Hh + j * 32);
    }

    float xa[2][4], xb[2][4];
    {
        const unsigned short* xr = xg + (size_t)(row0 + lrA) * G
                                 + wg_n * 16 + l15;
        #pragma unroll
        for (int nb = 0; nb < 4; ++nb) {
            xa[0][nb] = bf2f(xr[nb * Hh]);
            xa[1][nb] = bf2f(xr[G + nb * Hh]);
        }
    }

#define WRC(W_, C_)                                                            \
    if (((C_) >> 1) != (W_)) {                                                 \
        _Pragma("unroll")                                                      \
        for (int nb = 0; nb < 4; ++nb)                                         \
            redsum[((C_) * 3 + (((W_) > ((C_) >> 1)) ? (W_)-1 : (W_))) * 256   \
                   + nb * 64 + lane] = acc[(C_) >> 2][nb][(C_) & 3];           \
    }

#define SPILL(W_)                                                              \
    do {                                                                       \
        _Pragma("unroll")                                                      \
        for (int nb = 0; nb < 4; ++nb) {                                       \
            own0[nb] = acc[(2 * (W_)) >> 2][nb][(2 * (W_)) & 3];               \
            own1[nb] = acc[(2 * (W_) + 1) >> 2][nb][(2 * (W_) + 1) & 3];       \
        }                                                                      \
        WRC(W_, 0); WRC(W_, 1); WRC(W_, 2); WRC(W_, 3);                        \
        WRC(W_, 4); WRC(W_, 5); WRC(W_, 6); WRC(W_, 7);                        \
    } while (0)

#define LSTM_STEP(T, XC, XN)                                                   \
    do {                                                                       \
        const int t_ = (T);                                                    \
        floatx4 acc[2][4];                                                     \
        _Pragma("unroll")                                                      \
        for (int i = 0; i < 2; ++i)                                            \
            _Pragma("unroll")                                                  \
            for (int j = 0; j < 4; ++j) acc[i][j] = (floatx4)0.f;              \
        if (t_ > 0) {                                                          \
            if (tid < 8) {                                                     \
                const unsigned* fl = flags + (size_t)(wg_m * 8 + tid) * 16;    \
                unsigned need = 8u * (unsigned)t_;                             \
                while (__hip_atomic_load(fl, __ATOMIC_RELAXED,                 \
                                         __HIP_MEMORY_SCOPE_AGENT) < need)     \
                    __builtin_amdgcn_s_sleep(1);                               \
            }                                                                  \
            __syncthreads();                                                   \
            asm volatile("" ::: "memory");                                     \
            const unsigned short* hprev = hsb + (size_t)(t_ - 1) * (Bb * Hh);  \
            if (rotsel == 0)                                                   \
                gate_mfma<0>(hprev, wreg, row0, wave, l15, kq, acc);           \
            else if (rotsel == 1)                                              \
                gate_mfma<2>(hprev, wreg, row0, wave, l15, kq, acc);           \
            else if (rotsel == 2)                                              \
                gate_mfma<4>(hprev, wreg, row0, wave, l15, kq, acc);           \
            else                                                               \
                gate_mfma<6>(hprev, wreg, row0, wave, l15, kq, acc);           \
        }                                                                      \
        float own0[4], own1[4];                                                \
        if (wave == 0)      SPILL(0);                                          \
        else if (wave == 1) SPILL(1);                                          \
        else if (wave == 2) SPILL(2);                                          \
        else                SPILL(3);                                          \
        __syncthreads();                                                       \
        float gA[4], gB[4];                                                    \
        {                                                                      \
            const int cA = wave * 2;                                           \
            _Pragma("unroll")                                                  \
            for (int nb = 0; nb < 4; ++nb) {                                   \
                int bA = (cA * 3) * 256 + nb * 64 + lane;                      \
                gA[nb] = own0[nb] + redsum[bA] + redsum[bA + 256]              \
                       + redsum[bA + 512] + XC[0][nb];                         \
                int bB = ((cA + 1) * 3) * 256 + nb * 64 + lane;                \
                gB[nb] = own1[nb] + redsum[bB] + redsum[bB + 256]              \
                       + redsum[bB + 512] + XC[1][nb];                         \
            }                                                                  \
        }                                                                      \
        unsigned short* ht = hsb + (size_t)t_ * (Bb * Hh);                     \
        {                                                                      \
            float si = sigmoid_fast(gA[0]);                                    \
            float sf = sigmoid_fast(gA[1]);                                    \
            float tg = tanh_fast(gA[2]);                                       \
            float so = sigmoid_fast(gA[3]);                                    \
            float cn = sf * cell0 + si * tg;                                   \
            cell0 = cn;                                                        \
            float h = so * tanh_fast(cn);                                      \
            __hip_atomic_store(&ht[(size_t)(row0 + lrA) * Hh + hcol], f2bf(h), \
                               __ATOMIC_RELAXED, __HIP_MEMORY_SCOPE_AGENT);    \
        }                                                                      \
        {                                                                      \
            float si = sigmoid_fast(gB[0]);                                    \
            float sf = sigmoid_fast(gB[1]);                                    \
            float tg = tanh_fast(gB[2]);                                       \
            float so = sigmoid_fast(gB[3]);                                    \
            float cn = sf * cell1 + si * tg;                                   \
            cell1 = cn;                                                        \
            float h = so * tanh_fast(cn);                                      \
            __hip_atomic_store(&ht[(size_t)(row0 + lrB) * Hh + hcol], f2bf(h), \
                               __ATOMIC_RELAXED, __HIP_MEMORY_SCOPE_AGENT);    \
        }                                                                      \
        __builtin_amdgcn_sched_barrier(0);                                     \
        if (t_ + 1 < Tt) {   /* xg prefetch: YOUNGEST VMEM (after stores) */   \
            const unsigned short* xr = xg + (size_t)(t_ + 1) * (Bb * G)        \
                + (size_t)(row0 + lrA) * G + wg_n * 16 + l15;                  \
            _Pragma("unroll")                                                  \
            for (int nb = 0; nb < 4; ++nb) {                                   \
                XN[0][nb] = bf2f(xr[nb * Hh]);                                 \
                XN[1][nb] = bf2f(xr[G + nb * Hh]);                             \
            }                                                                  \
        }                                                                      \
        __builtin_amdgcn_sched_barrier(0);                                     \
        if (t_ < Tt - 1) {                                                     \
            /* 2 h stores (oldest) + 8 xg loads outstanding: wait stores */    \
            asm volatile("s_waitcnt vmcnt(8)" ::: "memory");                   \
            __builtin_amdgcn_sched_barrier(0);                                 \
            __builtin_amdgcn_s_barrier();                                      \
            __builtin_amdgcn_sched_barrier(0);                                 \
            if (tid == 0)                                                      \
                __hip_atomic_fetch_add(myctr, 1u, __ATOMIC_RELAXED,            \
                                       __HIP_MEMORY_SCOPE_AGENT);              \
        }                                                                      \
    } while (0)

    for (int tt = 0; tt < Tt; tt += 2) {
        LSTM_STEP(tt,     xa, xb);
        LSTM_STEP(tt + 1, xb, xa);
    }
#undef LSTM_STEP
#undef SPILL
#undef WRC
}

// ---------------------------------------------------------------------------
extern "C" void kernel_launch(void* const* d_in, const int* in_sizes, int n_in,
                              void* d_out, int out_size, void* d_ws, size_t ws_size,
                              hipStream_t stream) {
    const float* features = (const float*)d_in[0];
    const int*   captions = (const int*)d_in[1];
    const float* embed_W  = (const float*)d_in[2];
    const float* W_ih     = (const float*)d_in[3];
    const float* W_hh     = (const float*)d_in[4];
    const float* b_ih     = (const float*)d_in[5];
    const float* b_hh     = (const float*)d_in[6];
    const float* fc_W     = (const float*)d_in[7];
    const float* fc_b     = (const float*)d_in[8];
    float* out = (float*)d_out;

    unsigned short* xsb  = (unsigned short*)d_ws;          // [8192][512]
    unsigned short* wihb = xsb  + (size_t)Tt * Bb * Ee;    // [4096][512]
    unsigned short* whhb = wihb + (size_t)G * Ee;          // [4096][1024]
    unsigned short* fcwb = whhb + (size_t)G * Hh;          // [10240][1024]
    unsigned short* hsb  = fcwb + (size_t)Vpad * Hh;       // [64][128][1024]
    unsigned short* xgb  = hsb + (size_t)Tt * Bb * Hh;     // [8192][4096] bf16
    unsigned* flags = (unsigned*)(xgb + (size_t)Tt * Bb * G); // 32 ctrs

    (void)hipMemsetAsync(flags, 0, 128 * 32 * sizeof(unsigned), stream);

    // 1) fused weight conversions + input gather (one dispatch)
    prep<<<10240, 256, 0, stream>>>(W_ih, W_hh, fc_W, features, captions,
                                    embed_W, wihb, whhb, fcwb, xsb);

    // 2) x_gates = bf16(xs @ W_ih^T + b_ih + b_hh)   (M=8192, N=4096, K=512)
    {
        dim3 grid(8192 / 256, G / 256);   // 32 x 16 = 512 wgs (%8 == 0)
        gemm256<1><<<grid, 512, 0, stream>>>(
            xsb, wihb, 8192, G, Ee, b_ih, b_hh, (void*)xgb);
    }

    // 3) persistent LSTM recurrence (one launch, 64 steps, all 256 CUs)
    lstm_persist<<<256, 256, 0, stream>>>(whhb, xgb, hsb, flags);

    // 4) out[b,t,v] = hs @ fc_W^T + fc_b   (M=8192, N=10000(pad 10240), K=1024)
    {
        dim3 grid(8192 / 256, Vpad / 256);  // 32 x 40 = 1280 wgs (%8 == 0)
        gemm256<2><<<grid, 512, 0, stream>>>(
            hsb, fcwb, 8192, Vv, Hh, fc_b, nullptr, (void*)out);
    }
}